// Round 17
// baseline (435.342 us; speedup 1.0000x reference)
//
#include <hip/hip_runtime.h>
#include <hip/hip_bf16.h>

#define N_CRYST 64
#define ATOMS_PER 32
#define NN 2048
#define NBRS 20
#define EE 40960
#define CC 128
#define HIDDIM 256
#define NBASIS 128
#define NLAYERS 8
#define LMAXV 6
#define KK 19
#define MAXZV 100
#define ZDIMV 256
#define FOUR_PI_F 12.566370614359172f

typedef unsigned short ushort_t;
typedef __attribute__((ext_vector_type(8))) short short8;
typedef __attribute__((ext_vector_type(4))) float floatx4;

__device__ __forceinline__ ushort_t f2us(float f) {
    union { float f; unsigned u; } x;
    x.f = f;
    unsigned r = (x.u + 0x7fffu + ((x.u >> 16) & 1u)) >> 16;
    return (ushort_t)r;
}
__device__ __forceinline__ float us2f(unsigned u) {  // low 16 bits = bf16
    return __uint_as_float(u << 16);
}

// ======== geometry: positions (LDS) + edge dist/dirn/Y + per-tile CSR + zc, one kernel ====
__global__ void k_geom(const float* __restrict__ frac, const float* __restrict__ lengths,
                       const float* __restrict__ angles, const int* __restrict__ ei,
                       const float* __restrict__ z, const float* __restrict__ zproj,
                       float* __restrict__ dist, float* __restrict__ dirn,
                       float* __restrict__ Yv, int* __restrict__ trp,
                       int* __restrict__ tloc, float* __restrict__ zc) {
    const int cr = blockIdx.x;
    const int t = threadIdx.x;  // 256
    __shared__ float posL[32][3];
    __shared__ int cnt[8][32], base[8][32];

    if (t < 32) {
        int n = cr * 32 + t;
        float la = lengths[cr * 3 + 0];
        float lb = lengths[cr * 3 + 1];
        float lc = lengths[cr * 3 + 2];
        const float D2R = 0.017453292519943295f;
        float aa = angles[cr * 3 + 0] * D2R;
        float ab = angles[cr * 3 + 1] * D2R;
        float ag = angles[cr * 3 + 2] * D2R;
        float ca = cosf(aa), cb = cosf(ab), cg = cosf(ag), sg = sinf(ag);
        float v3y = (ca - cb * cg) / sg;
        float v3z = sqrtf(fmaxf(1.0f - cb * cb - v3y * v3y, 1e-8f));
        float f0 = frac[n * 3 + 0];
        float f1 = frac[n * 3 + 1];
        float f2 = frac[n * 3 + 2];
        posL[t][0] = f0 * la + f1 * (lb * cg) + f2 * (lc * cb);
        posL[t][1] = f1 * (lb * sg) + f2 * (lc * v3y);
        posL[t][2] = f2 * (lc * v3z);
    }
    cnt[t >> 5][t & 31] = 0;
    __syncthreads();

    for (int j = t; j < 640; j += 256) {
        int e = cr * 640 + j;
        int s = ei[e] - cr * 32, d = ei[EE + e] - cr * 32;
        float vx = posL[s][0] - posL[d][0];
        float vy = posL[s][1] - posL[d][1];
        float vz = posL[s][2] - posL[d][2];
        float dd = sqrtf(vx * vx + vy * vy + vz * vz) + 1e-8f;
        float ix = vx / dd, iy = vy / dd, iz = vz / dd;
        dist[e] = dd;
        dirn[e * 3 + 0] = ix;
        dirn[e * 3 + 1] = iy;
        dirn[e * 3 + 2] = iz;

        float ct = iz;
        float rho = sqrtf(ix * ix + iy * iy) + 1e-12f;
        float cph = ix / rho, sph = iy / rho;
        float P0[LMAXV + 1], P1[LMAXV + 1];
        P0[0] = 1.0f;
        P0[1] = ct;
        #pragma unroll
        for (int l = 2; l <= LMAXV; l++)
            P0[l] = ((2 * l - 1) * ct * P0[l - 1] - (l - 1) * P0[l - 2]) / (float)l;
        P1[0] = 0.0f;
        P1[1] = -rho;
        P1[2] = -3.0f * ct * rho;
        #pragma unroll
        for (int l = 3; l <= LMAXV; l++)
            P1[l] = ((2 * l - 1) * ct * P1[l - 1] - l * P1[l - 2]) / (float)(l - 1);

        float* Ye = Yv + (size_t)e * KK;
        Ye[0] = 0.28209479177387814f;
        #pragma unroll
        for (int l = 1; l <= LMAXV; l++) {
            float K0 = sqrtf((2 * l + 1) / FOUR_PI_F);
            float K1 = sqrtf(2.0f * (2 * l + 1) / (FOUR_PI_F * l * (l + 1)));
            Ye[3 * l - 2] = K1 * P1[l] * sph;
            Ye[3 * l - 1] = K0 * P0[l];
            Ye[3 * l]     = K1 * P1[l] * cph;
        }
        atomicAdd(&cnt[j / 80][s], 1);
    }
    __syncthreads();

    if (t < 8) {  // prefix per tile
        int run = 0;
        for (int a = 0; a < 32; a++) {
            base[t][a] = run;
            trp[(cr * 8 + t) * 33 + a] = run;
            run += cnt[t][a];
        }
        trp[(cr * 8 + t) * 33 + 32] = run;
    }
    __syncthreads();
    cnt[t >> 5][t & 31] = 0;
    __syncthreads();
    for (int j = t; j < 640; j += 256) {
        int e = cr * 640 + j;
        int s = ei[e] - cr * 32;
        int tt = j / 80;
        int slot = base[tt][s] + atomicAdd(&cnt[tt][s], 1);
        tloc[(cr * 8 + tt) * 80 + slot] = j - tt * 80;
    }

    // ---- zc[cr][c] = z[cr,:] @ zproj[:,c]  (amortized into this resident block) ----
    if (t < CC) {
        float acc = 0.f;
        const float* zb = z + (size_t)cr * ZDIMV;
        for (int d = 0; d < ZDIMV; d++) acc += zb[d] * zproj[d * CC + t];
        zc[cr * CC + t] = acc;
    }
}

// ======== prep: weight transpose+cast | rbf (8-wide) | xbf init (4-wide), one kernel ======
#define WT_BLKS 3072   // (8*256*256 + 8*128*256)/256
#define RBF_BLKS 2560  // EE*16/256  (each thread -> 8 basis values)
#define XI_BLKS 4864   // NN*KK*CC/4/256 (each thread -> 4 outputs)
__global__ void k_prep(const float* __restrict__ W1, const float* __restrict__ Wd,
                       const float* __restrict__ W2,
                       ushort_t* __restrict__ WT1, ushort_t* __restrict__ WT2,
                       const float* __restrict__ dist, ushort_t* __restrict__ Abf,
                       const int* __restrict__ atype, const int* __restrict__ batch,
                       const float* __restrict__ emb, const float* __restrict__ zc,
                       ushort_t* __restrict__ xbf) {
    const int bid = blockIdx.x;
    const int t = threadIdx.x;
    if (bid < WT_BLKS) {
        int idx = bid * 256 + t;
        const int n1 = NLAYERS * HIDDIM * 256;
        if (idx < n1) {
            int l = idx >> 16;
            int r = idx & 65535;
            int n = r >> 8, k = r & 255;
            float v = (k < 128) ? W1[((size_t)l * CC + k) * HIDDIM + n]
                                : Wd[((size_t)l * NBASIS + (k - 128)) * HIDDIM + n];
            WT1[idx] = f2us(v);
        } else {
            int j = idx - n1;
            int l = j >> 15;
            int r = j & 32767;
            int n = r >> 8, k = r & 255;
            WT2[j] = f2us(W2[((size_t)l * HIDDIM + k) * CC + n]);
        }
    } else if (bid < WT_BLKS + RBF_BLKS) {
        int idx = (bid - WT_BLKS) * 256 + t;      // 0 .. EE*16-1
        int e = idx >> 4, j8 = (idx & 15) * 8;
        const float width = 8.0f / 127.0f;
        const float invw = 127.0f / 8.0f;
        float dd = dist[e];
        short8 v;
        #pragma unroll
        for (int jj = 0; jj < 8; jj++) {
            float x = (dd - (float)(j8 + jj) * width) * invw;
            ((ushort_t*)&v)[jj] = f2us(__expf(-0.5f * x * x));
        }
        *(short8*)&Abf[(size_t)e * 256 + 128 + j8] = v;
    } else {
        int idx4 = (bid - WT_BLKS - RBF_BLKS) * 256 + t;
        int basei = idx4 * 4;
        if (basei >= NN * KK * CC) return;
        int n = basei / (KK * CC);
        int r = basei - n * (KK * CC);
        ushort_t v4[4];
        #pragma unroll
        for (int j = 0; j < 4; j++) {
            int rr = r + j;
            float v = 0.f;
            if (rr < CC) v = emb[atype[n] * CC + rr] + zc[batch[n] * CC + rr];
            v4[j] = f2us(v);
        }
        *(uint2*)&xbf[basei] = *(uint2*)v4;
    }
}

// ================= one LAYER per launch: 8-wave blocks; XCD-swizzled for L2 locality =====
// grid 512, block 512 (8 waves). Latency-chain trims vs round-14:
//  * first barrier REMOVED: s-prologue reads Y directly from global (broadcast, L2-hot);
//    Ylds staging overlaps and is covered by barriers (1)-(5) before aggregation reads.
//  * xold (aggregation's 19 xbfin reads/thread) hoisted before barrier (2) — 3 phases of
//    MFMA/VALU cover their latency instead of issuing fully exposed after barrier (5).
// LDS 47360 B: As/Hs[80][256] swizzled @0 (40960) | Ms[80][132] @0 | Ylds[80][20] @40960.
__global__ __launch_bounds__(512, 2) void k_layer(const int* __restrict__ trp,
                                                  const int* __restrict__ tloc,
                                                  const float* __restrict__ Yv,
                                                  const ushort_t* __restrict__ Abf,
                                                  const ushort_t* __restrict__ WT1,
                                                  const ushort_t* __restrict__ WT2,
                                                  const ushort_t* __restrict__ xbfin,
                                                  ushort_t* __restrict__ xbfout) {
    __shared__ char smraw[47360];
    ushort_t* As  = (ushort_t*)smraw;        // [80][256] swizzled
    ushort_t* Hs  = (ushort_t*)smraw;        // aliases As after barrier
    ushort_t* Ms  = (ushort_t*)smraw;        // [80][132]
    float*   Ylds = (float*)(smraw + 40960); // [80][20], persists to aggregation

    const int t = threadIdx.x;               // 0..511
    const int bid = ((blockIdx.x & 7) << 6) | (blockIdx.x >> 3);  // XCD-crystal swizzle
    const int w = t >> 6, lane = t & 63;     // w: 0..7
    const int quad = lane >> 4, lrow = lane & 15;
    const int e0 = bid * 80;
    const int cr = bid >> 3;

    // ---- stage Y [80][20] (+ zero pad col 19); NO barrier — consumers of Ylds are
    //      after barriers (1)-(5); the s-prologue reads Yv from global instead ----
    const float* Yb = Yv + (size_t)e0 * KK;
    #pragma unroll
    for (int j = 0; j < 3; j++) {
        int i = t + j * 512;
        if (i < 80 * KK) Ylds[(i / KK) * 20 + (i % KK)] = Yb[i];
    }
    if (t < 80) Ylds[t * 20 + 19] = 0.f;

    // ---- issue rbf A-half loads (1280 short8 over 512 threads) ----
    short8 arg[3];
    #pragma unroll
    for (int i = 0; i < 3; i++) {
        int idx = i * 512 + t;
        if (idx < 1280) {
            int r = idx >> 4, g16 = idx & 15;
            arg[i] = *(const short8*)(Abf + (size_t)(e0 + r) * 256 + 128 + g16 * 8);
        }
    }

    // ---- s-prologue: s[e][c] = sum_k Y[e,k]*xbf[src,k,c] -> As cols [0,128) swizzled ----
    const int c2 = lane * 2;
    const int sgrp = lane >> 2;        // 8-col group 0..15
    const int soff = (lane & 3) * 2;   // within-group ushort offset
    #pragma unroll 1
    for (int a8 = 0; a8 < 4; a8++) {
        const int a = w * 4 + a8;
        const int i0 = trp[bid * 33 + a];
        const int i1 = trp[bid * 33 + a + 1];
        if (i0 == i1) continue;
        const ushort_t* xsrc = xbfin + (size_t)(cr * 32 + a) * (KK * CC) + c2;
        float2 xr[KK];
        #pragma unroll
        for (int k = 0; k < KK; k++) {
            unsigned u = *(const unsigned*)(xsrc + k * CC);
            xr[k] = make_float2(us2f(u & 0xffffu), us2f(u >> 16));
        }
        for (int i = i0; i < i1; i++) {
            const int r = tloc[bid * 80 + i];
            const float* yp = Yv + (size_t)(e0 + r) * KK;   // global broadcast read
            float ax = 0.f, ay = 0.f;
            #pragma unroll
            for (int k = 0; k < KK; k++) {
                float y = yp[k];
                ax += y * xr[k].x;
                ay += y * xr[k].y;
            }
            unsigned pk = (unsigned)f2us(ax) | (((unsigned)f2us(ay)) << 16);
            *(unsigned*)&As[r * 256 + ((sgrp ^ (r & 7)) << 3) + soff] = pk;
        }
    }

    // ---- write rbf half (swizzled, groups 16..31) ----
    #pragma unroll
    for (int i = 0; i < 3; i++) {
        int idx = i * 512 + t;
        if (idx < 1280) {
            int r = idx >> 4, g = 16 + (idx & 15);
            *(short8*)&As[r * 256 + ((g ^ (r & 7)) << 3)] = arg[i];
        }
    }

    // ---- B1 prologue (steps 0,1): wave owns 32 cols of 256 ----
    const ushort_t* W1w = WT1 + (size_t)(w * 32) * 256;
    short8 bp0[2], bp1[2];
    #pragma unroll
    for (int ni = 0; ni < 2; ni++) {
        bp0[ni] = *(const short8*)(W1w + (size_t)(ni * 16 + lrow) * 256 + quad * 8);
        bp1[ni] = *(const short8*)(W1w + (size_t)(ni * 16 + lrow) * 256 + 32 + quad * 8);
    }
    __syncthreads();   // (1) As + Ylds complete

    // ---- GEMM1: 8 k-steps of 32, 2-deep B pipeline ----
    floatx4 acc[5][2];
    #pragma unroll
    for (int mi = 0; mi < 5; mi++)
        #pragma unroll
        for (int ni = 0; ni < 2; ni++) acc[mi][ni] = (floatx4){0.f, 0.f, 0.f, 0.f};

    #pragma unroll
    for (int s8 = 0; s8 < 8; s8++) {
        short8 bcur[2];
        if (s8 & 1) {
            #pragma unroll
            for (int ni = 0; ni < 2; ni++) bcur[ni] = bp1[ni];
            if (s8 < 6) {
                const int kn = (s8 + 2) * 32 + quad * 8;
                #pragma unroll
                for (int ni = 0; ni < 2; ni++)
                    bp1[ni] = *(const short8*)(W1w + (size_t)(ni * 16 + lrow) * 256 + kn);
            }
        } else {
            #pragma unroll
            for (int ni = 0; ni < 2; ni++) bcur[ni] = bp0[ni];
            if (s8 < 6) {
                const int kn = (s8 + 2) * 32 + quad * 8;
                #pragma unroll
                for (int ni = 0; ni < 2; ni++)
                    bp0[ni] = *(const short8*)(W1w + (size_t)(ni * 16 + lrow) * 256 + kn);
            }
        }
        const int grp = s8 * 4 + quad;
        short8 af[5];
        #pragma unroll
        for (int mi = 0; mi < 5; mi++) {
            const int r = mi * 16 + lrow;
            af[mi] = *(const short8*)&As[r * 256 + ((grp ^ (r & 7)) << 3)];
        }
        __builtin_amdgcn_s_setprio(1);
        #pragma unroll
        for (int ni = 0; ni < 2; ni++)
            #pragma unroll
            for (int mi = 0; mi < 5; mi++)
                acc[mi][ni] = __builtin_amdgcn_mfma_f32_16x16x32_bf16(
                    af[mi], bcur[ni], acc[mi][ni], 0, 0, 0);
        __builtin_amdgcn_s_setprio(0);
    }

    // ---- B2 prologue + xold prefetch before the barrier (hide under silu/GEMM2) ----
    const ushort_t* W2w = WT2 + (size_t)(w * 16) * 256;
    short8 bq0, bq1;
    bq0 = *(const short8*)(W2w + (size_t)lrow * 256 + quad * 8);
    bq1 = *(const short8*)(W2w + (size_t)lrow * 256 + 32 + quad * 8);

    const int node = t >> 7;
    const int cq = t & 127;
    const int ng = bid * 4 + node;
    const ushort_t* xbi = xbfin + (size_t)ng * (KK * CC) + cq;
    float xold[KK];
    #pragma unroll
    for (int k = 0; k < KK; k++) xold[k] = us2f((unsigned)xbi[k * CC]);
    __syncthreads();   // (2) As reads done before Hs overwrite

    // ---- silu -> Hs (swizzled) ----
    #pragma unroll
    for (int mi = 0; mi < 5; mi++) {
        const int row = mi * 16 + quad * 4;
        #pragma unroll
        for (int ni = 0; ni < 2; ni++) {
            const int col = w * 32 + ni * 16 + lrow;
            #pragma unroll
            for (int r = 0; r < 4; r++) {
                float v = acc[mi][ni][r];
                v = v * __builtin_amdgcn_rcpf(1.0f + __expf(-v));
                const int rr = row + r;
                Hs[rr * 256 + ((((col >> 3) ^ (rr & 7)) << 3) | (col & 7))] = f2us(v);
            }
        }
    }
    __syncthreads();   // (3) Hs complete

    // ---- GEMM2: 8 k-steps of 32, 2-deep B pipeline ----
    floatx4 macc[5];
    #pragma unroll
    for (int mi = 0; mi < 5; mi++) macc[mi] = (floatx4){0.f, 0.f, 0.f, 0.f};

    #pragma unroll
    for (int s8 = 0; s8 < 8; s8++) {
        short8 bcur;
        if (s8 & 1) {
            bcur = bq1;
            if (s8 < 6) {
                const int kn = (s8 + 2) * 32 + quad * 8;
                bq1 = *(const short8*)(W2w + (size_t)lrow * 256 + kn);
            }
        } else {
            bcur = bq0;
            if (s8 < 6) {
                const int kn = (s8 + 2) * 32 + quad * 8;
                bq0 = *(const short8*)(W2w + (size_t)lrow * 256 + kn);
            }
        }
        const int grp = s8 * 4 + quad;
        short8 af[5];
        #pragma unroll
        for (int mi = 0; mi < 5; mi++) {
            const int r = mi * 16 + lrow;
            af[mi] = *(const short8*)&Hs[r * 256 + ((grp ^ (r & 7)) << 3)];
        }
        __builtin_amdgcn_s_setprio(1);
        #pragma unroll
        for (int mi = 0; mi < 5; mi++)
            macc[mi] = __builtin_amdgcn_mfma_f32_16x16x32_bf16(
                af[mi], bcur, macc[mi], 0, 0, 0);
        __builtin_amdgcn_s_setprio(0);
    }
    __syncthreads();   // (4) Hs reads done before Ms overwrite

    // ---- macc -> Ms bf16 [80][132] (Ylds already staged, untouched) ----
    #pragma unroll
    for (int mi = 0; mi < 5; mi++) {
        const int row = mi * 16 + quad * 4;
        const int col = w * 16 + lrow;
        #pragma unroll
        for (int r = 0; r < 4; r++)
            Ms[(row + r) * 132 + col] = f2us(macc[mi][r]);
    }
    __syncthreads();   // (5)

    // ---- aggregation: thread = (node, col); xbfout = xold + agg/NBRS (bf16 in/out) ----
    ushort_t* xbo = xbfout + (size_t)ng * (KK * CC) + cq;

    float xacc[KK];
    #pragma unroll
    for (int k = 0; k < KK; k++) xacc[k] = 0.f;

    #pragma unroll 4
    for (int e = 0; e < NBRS; e++) {
        const int eg = node * NBRS + e;
        const float m0 = us2f((unsigned)Ms[eg * 132 + cq]);
        const float* yp = Ylds + eg * 20;
        #pragma unroll
        for (int kq = 0; kq < 5; kq++) {
            float4 y = *(const float4*)(yp + kq * 4);
            const int k = kq * 4;
            xacc[k + 0] += y.x * m0;
            xacc[k + 1] += y.y * m0;
            xacc[k + 2] += y.z * m0;
            if (kq < 4) xacc[k + 3] += y.w * m0;
        }
    }
    const float s = 1.0f / (float)NBRS;
    #pragma unroll
    for (int k = 0; k < KK; k++) {
        float nv = xold[k] + xacc[k] * s;
        xbo[k * CC] = f2us(nv);
    }
}

// ======== head: coord_diff (blocks 0..511) + atom logits (blocks 512..1311) ========
#define COORD_BLKS 512
__global__ void k_head(const int* __restrict__ ei, const ushort_t* __restrict__ xbf,
                       const float* __restrict__ wf, const float* __restrict__ dirn,
                       const float* __restrict__ Wa, const float* __restrict__ ba,
                       float* __restrict__ out) {
    const int bid = blockIdx.x;
    const int t = threadIdx.x;  // 256
    if (bid < COORD_BLKS) {
        // 4 nodes per block, 64 threads each
        __shared__ float fs[4][NBRS];
        __shared__ float wsh[CC];
        const int g = t >> 6, lane = t & 63;
        const int n = bid * 4 + g;
        if (t < CC) wsh[t] = wf[t];
        __syncthreads();
        if (lane < NBRS) {
            int e = n * NBRS + lane;
            int sidx = ei[e];
            const ushort_t* xs = xbf + (size_t)sidx * (KK * CC);
            const ushort_t* xd = xbf + (size_t)n * (KK * CC);
            float acc = 0.0f;
            for (int c = 0; c < CC; c++)
                acc += (us2f((unsigned)xs[c]) - us2f((unsigned)xd[c])) * wsh[c];
            fs[g][lane] = acc;
        }
        __syncthreads();
        if (lane < 3) {
            float acc = 0.0f;
            #pragma unroll
            for (int j = 0; j < NBRS; j++)
                acc += fs[g][j] * dirn[(size_t)(n * NBRS + j) * 3 + lane];
            out[n * 3 + lane] = acc;
        }
    } else {
        int idx = (bid - COORD_BLKS) * 256 + t;
        if (idx >= NN * MAXZV) return;
        int n = idx / MAXZV, a = idx - n * MAXZV;
        float acc = ba[a];
        const ushort_t* hn = xbf + (size_t)n * (KK * CC);
        for (int c = 0; c < CC; c++) acc += us2f((unsigned)hn[c]) * Wa[c * MAXZV + a];
        out[NN * 3 + idx] = acc;
    }
}

extern "C" void kernel_launch(void* const* d_in, const int* in_sizes, int n_in,
                              void* d_out, int out_size, void* d_ws, size_t ws_size,
                              hipStream_t stream) {
    (void)in_sizes; (void)n_in; (void)out_size; (void)ws_size;
    const float* z       = (const float*)d_in[0];
    const float* frac    = (const float*)d_in[1];
    const int*   atype   = (const int*)d_in[2];
    const float* lengths = (const float*)d_in[4];
    const float* angles  = (const float*)d_in[5];
    const int*   batch   = (const int*)d_in[6];
    const int*   ei      = (const int*)d_in[7];
    const float* emb     = (const float*)d_in[8];
    const float* zproj   = (const float*)d_in[9];
    const float* Wd      = (const float*)d_in[10];
    const float* W1      = (const float*)d_in[11];
    const float* W2      = (const float*)d_in[12];
    const float* Wa      = (const float*)d_in[13];
    const float* ba      = (const float*)d_in[14];
    const float* wf      = (const float*)d_in[15];
    float* out = (float*)d_out;

    float* ws = (float*)d_ws;
    float* dist = ws; ws += EE;
    float* dirn = ws; ws += EE * 3;
    float* Yv   = ws; ws += (size_t)EE * KK + 4;
    float* zc   = ws; ws += N_CRYST * CC;
    ushort_t* xbfA = (ushort_t*)ws; ws += (size_t)NN * KK * CC / 2;   // bf16 x ping
    ushort_t* xbfB = (ushort_t*)ws; ws += (size_t)NN * KK * CC / 2;   // bf16 x pong
    int* trp  = (int*)ws;                         // 512*33
    int* tloc = trp + 512 * 33;                   // 512*80
    ushort_t* Abf  = (ushort_t*)(tloc + 512 * 80); // [E][256]: rbf in cols 128..255
    ushort_t* WT1  = Abf + (size_t)EE * 256;      // [8][256][256]
    ushort_t* WT2  = WT1 + (size_t)NLAYERS * 256 * 256;  // [8][128][256]

    k_geom<<<N_CRYST, 256, 0, stream>>>(frac, lengths, angles, ei, z, zproj,
                                        dist, dirn, Yv, trp, tloc, zc);
    k_prep<<<WT_BLKS + RBF_BLKS + XI_BLKS, 256, 0, stream>>>(W1, Wd, W2, WT1, WT2,
                                                             dist, Abf, atype, batch,
                                                             emb, zc, xbfA);

    for (int l = 0; l < NLAYERS; l++) {
        const ushort_t* xbi = (l & 1) ? xbfB : xbfA;
        ushort_t*       xbo = (l & 1) ? xbfA : xbfB;
        k_layer<<<512, 512, 0, stream>>>(trp, tloc, Yv, Abf,
                                         WT1 + (size_t)l * 256 * 256,
                                         WT2 + (size_t)l * CC * HIDDIM,
                                         xbi, xbo);
    }
    // after 8 layers (even count) the final x is in xbfA

    k_head<<<COORD_BLKS + (NN * MAXZV) / 256, 256, 0, stream>>>(ei, xbfA, wf, dirn,
                                                                Wa, ba, out);
}

// Round 18
// 410.267 us; speedup vs baseline: 1.0611x; 1.0611x over previous
//
#include <hip/hip_runtime.h>
#include <hip/hip_bf16.h>

#define N_CRYST 64
#define ATOMS_PER 32
#define NN 2048
#define NBRS 20
#define EE 40960
#define CC 128
#define HIDDIM 256
#define NBASIS 128
#define NLAYERS 8
#define LMAXV 6
#define KK 19
#define MAXZV 100
#define ZDIMV 256
#define FOUR_PI_F 12.566370614359172f

typedef unsigned short ushort_t;
typedef __attribute__((ext_vector_type(8))) short short8;
typedef __attribute__((ext_vector_type(4))) float floatx4;

__device__ __forceinline__ ushort_t f2us(float f) {
    union { float f; unsigned u; } x;
    x.f = f;
    unsigned r = (x.u + 0x7fffu + ((x.u >> 16) & 1u)) >> 16;
    return (ushort_t)r;
}
__device__ __forceinline__ float us2f(unsigned u) {  // low 16 bits = bf16
    return __uint_as_float(u << 16);
}

// ======== geometry: positions (LDS) + edge dist/dirn/Y + per-tile CSR + zc, one kernel ====
__global__ void k_geom(const float* __restrict__ frac, const float* __restrict__ lengths,
                       const float* __restrict__ angles, const int* __restrict__ ei,
                       const float* __restrict__ z, const float* __restrict__ zproj,
                       float* __restrict__ dist, float* __restrict__ dirn,
                       float* __restrict__ Yv, int* __restrict__ trp,
                       int* __restrict__ tloc, float* __restrict__ zc) {
    const int cr = blockIdx.x;
    const int t = threadIdx.x;  // 256
    __shared__ float posL[32][3];
    __shared__ int cnt[8][32], base[8][32];

    if (t < 32) {
        int n = cr * 32 + t;
        float la = lengths[cr * 3 + 0];
        float lb = lengths[cr * 3 + 1];
        float lc = lengths[cr * 3 + 2];
        const float D2R = 0.017453292519943295f;
        float aa = angles[cr * 3 + 0] * D2R;
        float ab = angles[cr * 3 + 1] * D2R;
        float ag = angles[cr * 3 + 2] * D2R;
        float ca = cosf(aa), cb = cosf(ab), cg = cosf(ag), sg = sinf(ag);
        float v3y = (ca - cb * cg) / sg;
        float v3z = sqrtf(fmaxf(1.0f - cb * cb - v3y * v3y, 1e-8f));
        float f0 = frac[n * 3 + 0];
        float f1 = frac[n * 3 + 1];
        float f2 = frac[n * 3 + 2];
        posL[t][0] = f0 * la + f1 * (lb * cg) + f2 * (lc * cb);
        posL[t][1] = f1 * (lb * sg) + f2 * (lc * v3y);
        posL[t][2] = f2 * (lc * v3z);
    }
    cnt[t >> 5][t & 31] = 0;
    __syncthreads();

    for (int j = t; j < 640; j += 256) {
        int e = cr * 640 + j;
        int s = ei[e] - cr * 32, d = ei[EE + e] - cr * 32;
        float vx = posL[s][0] - posL[d][0];
        float vy = posL[s][1] - posL[d][1];
        float vz = posL[s][2] - posL[d][2];
        float dd = sqrtf(vx * vx + vy * vy + vz * vz) + 1e-8f;
        float ix = vx / dd, iy = vy / dd, iz = vz / dd;
        dist[e] = dd;
        dirn[e * 3 + 0] = ix;
        dirn[e * 3 + 1] = iy;
        dirn[e * 3 + 2] = iz;

        float ct = iz;
        float rho = sqrtf(ix * ix + iy * iy) + 1e-12f;
        float cph = ix / rho, sph = iy / rho;
        float P0[LMAXV + 1], P1[LMAXV + 1];
        P0[0] = 1.0f;
        P0[1] = ct;
        #pragma unroll
        for (int l = 2; l <= LMAXV; l++)
            P0[l] = ((2 * l - 1) * ct * P0[l - 1] - (l - 1) * P0[l - 2]) / (float)l;
        P1[0] = 0.0f;
        P1[1] = -rho;
        P1[2] = -3.0f * ct * rho;
        #pragma unroll
        for (int l = 3; l <= LMAXV; l++)
            P1[l] = ((2 * l - 1) * ct * P1[l - 1] - l * P1[l - 2]) / (float)(l - 1);

        float* Ye = Yv + (size_t)e * KK;
        Ye[0] = 0.28209479177387814f;
        #pragma unroll
        for (int l = 1; l <= LMAXV; l++) {
            float K0 = sqrtf((2 * l + 1) / FOUR_PI_F);
            float K1 = sqrtf(2.0f * (2 * l + 1) / (FOUR_PI_F * l * (l + 1)));
            Ye[3 * l - 2] = K1 * P1[l] * sph;
            Ye[3 * l - 1] = K0 * P0[l];
            Ye[3 * l]     = K1 * P1[l] * cph;
        }
        atomicAdd(&cnt[j / 80][s], 1);
    }
    __syncthreads();

    if (t < 8) {  // prefix per tile
        int run = 0;
        for (int a = 0; a < 32; a++) {
            base[t][a] = run;
            trp[(cr * 8 + t) * 33 + a] = run;
            run += cnt[t][a];
        }
        trp[(cr * 8 + t) * 33 + 32] = run;
    }
    __syncthreads();
    cnt[t >> 5][t & 31] = 0;
    __syncthreads();
    for (int j = t; j < 640; j += 256) {
        int e = cr * 640 + j;
        int s = ei[e] - cr * 32;
        int tt = j / 80;
        int slot = base[tt][s] + atomicAdd(&cnt[tt][s], 1);
        tloc[(cr * 8 + tt) * 80 + slot] = j - tt * 80;
    }

    // ---- zc[cr][c] = z[cr,:] @ zproj[:,c]  (amortized into this resident block) ----
    if (t < CC) {
        float acc = 0.f;
        const float* zb = z + (size_t)cr * ZDIMV;
        for (int d = 0; d < ZDIMV; d++) acc += zb[d] * zproj[d * CC + t];
        zc[cr * CC + t] = acc;
    }
}

// ======== prep: weight transpose+cast | rbf (8-wide) | xbf init (4-wide), one kernel ======
#define WT_BLKS 3072   // (8*256*256 + 8*128*256)/256
#define RBF_BLKS 2560  // EE*16/256  (each thread -> 8 basis values)
#define XI_BLKS 4864   // NN*KK*CC/4/256 (each thread -> 4 outputs)
__global__ void k_prep(const float* __restrict__ W1, const float* __restrict__ Wd,
                       const float* __restrict__ W2,
                       ushort_t* __restrict__ WT1, ushort_t* __restrict__ WT2,
                       const float* __restrict__ dist, ushort_t* __restrict__ Abf,
                       const int* __restrict__ atype, const int* __restrict__ batch,
                       const float* __restrict__ emb, const float* __restrict__ zc,
                       ushort_t* __restrict__ xbf) {
    const int bid = blockIdx.x;
    const int t = threadIdx.x;
    if (bid < WT_BLKS) {
        int idx = bid * 256 + t;
        const int n1 = NLAYERS * HIDDIM * 256;
        if (idx < n1) {
            int l = idx >> 16;
            int r = idx & 65535;
            int n = r >> 8, k = r & 255;
            float v = (k < 128) ? W1[((size_t)l * CC + k) * HIDDIM + n]
                                : Wd[((size_t)l * NBASIS + (k - 128)) * HIDDIM + n];
            WT1[idx] = f2us(v);
        } else {
            int j = idx - n1;
            int l = j >> 15;
            int r = j & 32767;
            int n = r >> 8, k = r & 255;
            WT2[j] = f2us(W2[((size_t)l * HIDDIM + k) * CC + n]);
        }
    } else if (bid < WT_BLKS + RBF_BLKS) {
        int idx = (bid - WT_BLKS) * 256 + t;      // 0 .. EE*16-1
        int e = idx >> 4, j8 = (idx & 15) * 8;
        const float width = 8.0f / 127.0f;
        const float invw = 127.0f / 8.0f;
        float dd = dist[e];
        short8 v;
        #pragma unroll
        for (int jj = 0; jj < 8; jj++) {
            float x = (dd - (float)(j8 + jj) * width) * invw;
            ((ushort_t*)&v)[jj] = f2us(__expf(-0.5f * x * x));
        }
        *(short8*)&Abf[(size_t)e * 256 + 128 + j8] = v;
    } else {
        int idx4 = (bid - WT_BLKS - RBF_BLKS) * 256 + t;
        int basei = idx4 * 4;
        if (basei >= NN * KK * CC) return;
        int n = basei / (KK * CC);
        int r = basei - n * (KK * CC);
        ushort_t v4[4];
        #pragma unroll
        for (int j = 0; j < 4; j++) {
            int rr = r + j;
            float v = 0.f;
            if (rr < CC) v = emb[atype[n] * CC + rr] + zc[batch[n] * CC + rr];
            v4[j] = f2us(v);
        }
        *(uint2*)&xbf[basei] = *(uint2*)v4;
    }
}

// ================= one LAYER per launch: 8-wave blocks; XCD-swizzled for L2 locality =====
// grid 512, block 512 (8 waves). bid = (blockIdx.x&7)*64 + blockIdx.x>>3 puts crystals
// 8c..8c+7 on XCD c -> a crystal's xbf slab + trp/tloc L2-resident for its 8 blocks.
// s_setprio(1) wraps MFMA clusters (2 co-resident blocks at different phases).
// LDS 47360 B: As/Hs[80][256] swizzled @0 (40960) | Ms[80][132] @0 | Ylds[80][20] @40960.
__global__ __launch_bounds__(512, 2) void k_layer(const int* __restrict__ trp,
                                                  const int* __restrict__ tloc,
                                                  const float* __restrict__ Yv,
                                                  const ushort_t* __restrict__ Abf,
                                                  const ushort_t* __restrict__ WT1,
                                                  const ushort_t* __restrict__ WT2,
                                                  const ushort_t* __restrict__ xbfin,
                                                  ushort_t* __restrict__ xbfout) {
    __shared__ char smraw[47360];
    ushort_t* As  = (ushort_t*)smraw;        // [80][256] swizzled
    ushort_t* Hs  = (ushort_t*)smraw;        // aliases As after barrier
    ushort_t* Ms  = (ushort_t*)smraw;        // [80][132]
    float*   Ylds = (float*)(smraw + 40960); // [80][20], persists to aggregation

    const int t = threadIdx.x;               // 0..511
    const int bid = ((blockIdx.x & 7) << 6) | (blockIdx.x >> 3);  // XCD-crystal swizzle
    const int w = t >> 6, lane = t & 63;     // w: 0..7
    const int quad = lane >> 4, lrow = lane & 15;
    const int e0 = bid * 80;
    const int cr = bid >> 3;

    // ---- stage Y [80][20] (+ zero pad col 19) ----
    const float* Yb = Yv + (size_t)e0 * KK;
    #pragma unroll
    for (int j = 0; j < 3; j++) {
        int i = t + j * 512;
        if (i < 80 * KK) Ylds[(i / KK) * 20 + (i % KK)] = Yb[i];
    }
    if (t < 80) Ylds[t * 20 + 19] = 0.f;
    __syncthreads();

    // ---- issue rbf A-half loads (1280 short8 over 512 threads) ----
    short8 arg[3];
    #pragma unroll
    for (int i = 0; i < 3; i++) {
        int idx = i * 512 + t;
        if (idx < 1280) {
            int r = idx >> 4, g16 = idx & 15;
            arg[i] = *(const short8*)(Abf + (size_t)(e0 + r) * 256 + 128 + g16 * 8);
        }
    }

    // ---- s-prologue: s[e][c] = sum_k Y[e,k]*xbf[src,k,c] -> As cols [0,128) swizzled ----
    const int c2 = lane * 2;
    const int sgrp = lane >> 2;        // 8-col group 0..15
    const int soff = (lane & 3) * 2;   // within-group ushort offset
    #pragma unroll 1
    for (int a8 = 0; a8 < 4; a8++) {
        const int a = w * 4 + a8;
        const int i0 = trp[bid * 33 + a];
        const int i1 = trp[bid * 33 + a + 1];
        if (i0 == i1) continue;
        const ushort_t* xsrc = xbfin + (size_t)(cr * 32 + a) * (KK * CC) + c2;
        float2 xr[KK];
        #pragma unroll
        for (int k = 0; k < KK; k++) {
            unsigned u = *(const unsigned*)(xsrc + k * CC);
            xr[k] = make_float2(us2f(u & 0xffffu), us2f(u >> 16));
        }
        for (int i = i0; i < i1; i++) {
            const int r = tloc[bid * 80 + i];
            const float* yp = Ylds + r * 20;
            float ax = 0.f, ay = 0.f;
            #pragma unroll
            for (int k = 0; k < KK; k++) {
                float y = yp[k];
                ax += y * xr[k].x;
                ay += y * xr[k].y;
            }
            unsigned pk = (unsigned)f2us(ax) | (((unsigned)f2us(ay)) << 16);
            *(unsigned*)&As[r * 256 + ((sgrp ^ (r & 7)) << 3) + soff] = pk;
        }
    }

    // ---- write rbf half (swizzled, groups 16..31) ----
    #pragma unroll
    for (int i = 0; i < 3; i++) {
        int idx = i * 512 + t;
        if (idx < 1280) {
            int r = idx >> 4, g = 16 + (idx & 15);
            *(short8*)&As[r * 256 + ((g ^ (r & 7)) << 3)] = arg[i];
        }
    }

    // ---- B1 prologue (steps 0,1): wave owns 32 cols of 256 ----
    const ushort_t* W1w = WT1 + (size_t)(w * 32) * 256;
    short8 bp0[2], bp1[2];
    #pragma unroll
    for (int ni = 0; ni < 2; ni++) {
        bp0[ni] = *(const short8*)(W1w + (size_t)(ni * 16 + lrow) * 256 + quad * 8);
        bp1[ni] = *(const short8*)(W1w + (size_t)(ni * 16 + lrow) * 256 + 32 + quad * 8);
    }
    __syncthreads();   // (1) As complete

    // ---- GEMM1: 8 k-steps of 32, 2-deep B pipeline ----
    floatx4 acc[5][2];
    #pragma unroll
    for (int mi = 0; mi < 5; mi++)
        #pragma unroll
        for (int ni = 0; ni < 2; ni++) acc[mi][ni] = (floatx4){0.f, 0.f, 0.f, 0.f};

    #pragma unroll
    for (int s8 = 0; s8 < 8; s8++) {
        short8 bcur[2];
        if (s8 & 1) {
            #pragma unroll
            for (int ni = 0; ni < 2; ni++) bcur[ni] = bp1[ni];
            if (s8 < 6) {
                const int kn = (s8 + 2) * 32 + quad * 8;
                #pragma unroll
                for (int ni = 0; ni < 2; ni++)
                    bp1[ni] = *(const short8*)(W1w + (size_t)(ni * 16 + lrow) * 256 + kn);
            }
        } else {
            #pragma unroll
            for (int ni = 0; ni < 2; ni++) bcur[ni] = bp0[ni];
            if (s8 < 6) {
                const int kn = (s8 + 2) * 32 + quad * 8;
                #pragma unroll
                for (int ni = 0; ni < 2; ni++)
                    bp0[ni] = *(const short8*)(W1w + (size_t)(ni * 16 + lrow) * 256 + kn);
            }
        }
        const int grp = s8 * 4 + quad;
        short8 af[5];
        #pragma unroll
        for (int mi = 0; mi < 5; mi++) {
            const int r = mi * 16 + lrow;
            af[mi] = *(const short8*)&As[r * 256 + ((grp ^ (r & 7)) << 3)];
        }
        __builtin_amdgcn_s_setprio(1);
        #pragma unroll
        for (int ni = 0; ni < 2; ni++)
            #pragma unroll
            for (int mi = 0; mi < 5; mi++)
                acc[mi][ni] = __builtin_amdgcn_mfma_f32_16x16x32_bf16(
                    af[mi], bcur[ni], acc[mi][ni], 0, 0, 0);
        __builtin_amdgcn_s_setprio(0);
    }

    // ---- B2 prologue before the barrier (hide under silu): wave owns 16 cols of 128 ----
    const ushort_t* W2w = WT2 + (size_t)(w * 16) * 256;
    short8 bq0, bq1;
    bq0 = *(const short8*)(W2w + (size_t)lrow * 256 + quad * 8);
    bq1 = *(const short8*)(W2w + (size_t)lrow * 256 + 32 + quad * 8);
    __syncthreads();   // (2) As reads done before Hs overwrite

    // ---- silu -> Hs (swizzled) ----
    #pragma unroll
    for (int mi = 0; mi < 5; mi++) {
        const int row = mi * 16 + quad * 4;
        #pragma unroll
        for (int ni = 0; ni < 2; ni++) {
            const int col = w * 32 + ni * 16 + lrow;
            #pragma unroll
            for (int r = 0; r < 4; r++) {
                float v = acc[mi][ni][r];
                v = v * __builtin_amdgcn_rcpf(1.0f + __expf(-v));
                const int rr = row + r;
                Hs[rr * 256 + ((((col >> 3) ^ (rr & 7)) << 3) | (col & 7))] = f2us(v);
            }
        }
    }
    __syncthreads();   // (3) Hs complete

    // ---- GEMM2: 8 k-steps of 32, 2-deep B pipeline ----
    floatx4 macc[5];
    #pragma unroll
    for (int mi = 0; mi < 5; mi++) macc[mi] = (floatx4){0.f, 0.f, 0.f, 0.f};

    #pragma unroll
    for (int s8 = 0; s8 < 8; s8++) {
        short8 bcur;
        if (s8 & 1) {
            bcur = bq1;
            if (s8 < 6) {
                const int kn = (s8 + 2) * 32 + quad * 8;
                bq1 = *(const short8*)(W2w + (size_t)lrow * 256 + kn);
            }
        } else {
            bcur = bq0;
            if (s8 < 6) {
                const int kn = (s8 + 2) * 32 + quad * 8;
                bq0 = *(const short8*)(W2w + (size_t)lrow * 256 + kn);
            }
        }
        const int grp = s8 * 4 + quad;
        short8 af[5];
        #pragma unroll
        for (int mi = 0; mi < 5; mi++) {
            const int r = mi * 16 + lrow;
            af[mi] = *(const short8*)&Hs[r * 256 + ((grp ^ (r & 7)) << 3)];
        }
        __builtin_amdgcn_s_setprio(1);
        #pragma unroll
        for (int mi = 0; mi < 5; mi++)
            macc[mi] = __builtin_amdgcn_mfma_f32_16x16x32_bf16(
                af[mi], bcur, macc[mi], 0, 0, 0);
        __builtin_amdgcn_s_setprio(0);
    }
    __syncthreads();   // (4) Hs reads done before Ms overwrite

    // ---- macc -> Ms bf16 [80][132] (Ylds already staged, untouched) ----
    #pragma unroll
    for (int mi = 0; mi < 5; mi++) {
        const int row = mi * 16 + quad * 4;
        const int col = w * 16 + lrow;
        #pragma unroll
        for (int r = 0; r < 4; r++)
            Ms[(row + r) * 132 + col] = f2us(macc[mi][r]);
    }
    __syncthreads();   // (5)

    // ---- aggregation: thread = (node, col); xbfout = xbfin + agg/NBRS (bf16 in/out) ----
    const int node = t >> 7;
    const int cq = t & 127;
    const int ng = bid * 4 + node;
    const ushort_t* xbi = xbfin + (size_t)ng * (KK * CC) + cq;
    ushort_t* xbo = xbfout + (size_t)ng * (KK * CC) + cq;

    float xold[KK];
    #pragma unroll
    for (int k = 0; k < KK; k++) xold[k] = us2f((unsigned)xbi[k * CC]);

    float xacc[KK];
    #pragma unroll
    for (int k = 0; k < KK; k++) xacc[k] = 0.f;

    #pragma unroll 4
    for (int e = 0; e < NBRS; e++) {
        const int eg = node * NBRS + e;
        const float m0 = us2f((unsigned)Ms[eg * 132 + cq]);
        const float* yp = Ylds + eg * 20;
        #pragma unroll
        for (int kq = 0; kq < 5; kq++) {
            float4 y = *(const float4*)(yp + kq * 4);
            const int k = kq * 4;
            xacc[k + 0] += y.x * m0;
            xacc[k + 1] += y.y * m0;
            xacc[k + 2] += y.z * m0;
            if (kq < 4) xacc[k + 3] += y.w * m0;
        }
    }
    const float s = 1.0f / (float)NBRS;
    #pragma unroll
    for (int k = 0; k < KK; k++) {
        float nv = xold[k] + xacc[k] * s;
        xbo[k * CC] = f2us(nv);
    }
}

// ======== head: coord_diff (blocks 0..511) + atom logits (blocks 512..1311) ========
#define COORD_BLKS 512
__global__ void k_head(const int* __restrict__ ei, const ushort_t* __restrict__ xbf,
                       const float* __restrict__ wf, const float* __restrict__ dirn,
                       const float* __restrict__ Wa, const float* __restrict__ ba,
                       float* __restrict__ out) {
    const int bid = blockIdx.x;
    const int t = threadIdx.x;  // 256
    if (bid < COORD_BLKS) {
        // 4 nodes per block, 64 threads each
        __shared__ float fs[4][NBRS];
        __shared__ float wsh[CC];
        const int g = t >> 6, lane = t & 63;
        const int n = bid * 4 + g;
        if (t < CC) wsh[t] = wf[t];
        __syncthreads();
        if (lane < NBRS) {
            int e = n * NBRS + lane;
            int sidx = ei[e];
            const ushort_t* xs = xbf + (size_t)sidx * (KK * CC);
            const ushort_t* xd = xbf + (size_t)n * (KK * CC);
            float acc = 0.0f;
            for (int c = 0; c < CC; c++)
                acc += (us2f((unsigned)xs[c]) - us2f((unsigned)xd[c])) * wsh[c];
            fs[g][lane] = acc;
        }
        __syncthreads();
        if (lane < 3) {
            float acc = 0.0f;
            #pragma unroll
            for (int j = 0; j < NBRS; j++)
                acc += fs[g][j] * dirn[(size_t)(n * NBRS + j) * 3 + lane];
            out[n * 3 + lane] = acc;
        }
    } else {
        int idx = (bid - COORD_BLKS) * 256 + t;
        if (idx >= NN * MAXZV) return;
        int n = idx / MAXZV, a = idx - n * MAXZV;
        float acc = ba[a];
        const ushort_t* hn = xbf + (size_t)n * (KK * CC);
        for (int c = 0; c < CC; c++) acc += us2f((unsigned)hn[c]) * Wa[c * MAXZV + a];
        out[NN * 3 + idx] = acc;
    }
}

extern "C" void kernel_launch(void* const* d_in, const int* in_sizes, int n_in,
                              void* d_out, int out_size, void* d_ws, size_t ws_size,
                              hipStream_t stream) {
    (void)in_sizes; (void)n_in; (void)out_size; (void)ws_size;
    const float* z       = (const float*)d_in[0];
    const float* frac    = (const float*)d_in[1];
    const int*   atype   = (const int*)d_in[2];
    const float* lengths = (const float*)d_in[4];
    const float* angles  = (const float*)d_in[5];
    const int*   batch   = (const int*)d_in[6];
    const int*   ei      = (const int*)d_in[7];
    const float* emb     = (const float*)d_in[8];
    const float* zproj   = (const float*)d_in[9];
    const float* Wd      = (const float*)d_in[10];
    const float* W1      = (const float*)d_in[11];
    const float* W2      = (const float*)d_in[12];
    const float* Wa      = (const float*)d_in[13];
    const float* ba      = (const float*)d_in[14];
    const float* wf      = (const float*)d_in[15];
    float* out = (float*)d_out;

    float* ws = (float*)d_ws;
    float* dist = ws; ws += EE;
    float* dirn = ws; ws += EE * 3;
    float* Yv   = ws; ws += (size_t)EE * KK + 4;
    float* zc   = ws; ws += N_CRYST * CC;
    ushort_t* xbfA = (ushort_t*)ws; ws += (size_t)NN * KK * CC / 2;   // bf16 x ping
    ushort_t* xbfB = (ushort_t*)ws; ws += (size_t)NN * KK * CC / 2;   // bf16 x pong
    int* trp  = (int*)ws;                         // 512*33
    int* tloc = trp + 512 * 33;                   // 512*80
    ushort_t* Abf  = (ushort_t*)(tloc + 512 * 80); // [E][256]: rbf in cols 128..255
    ushort_t* WT1  = Abf + (size_t)EE * 256;      // [8][256][256]
    ushort_t* WT2  = WT1 + (size_t)NLAYERS * 256 * 256;  // [8][128][256]

    k_geom<<<N_CRYST, 256, 0, stream>>>(frac, lengths, angles, ei, z, zproj,
                                        dist, dirn, Yv, trp, tloc, zc);
    k_prep<<<WT_BLKS + RBF_BLKS + XI_BLKS, 256, 0, stream>>>(W1, Wd, W2, WT1, WT2,
                                                             dist, Abf, atype, batch,
                                                             emb, zc, xbfA);

    for (int l = 0; l < NLAYERS; l++) {
        const ushort_t* xbi = (l & 1) ? xbfB : xbfA;
        ushort_t*       xbo = (l & 1) ? xbfA : xbfB;
        k_layer<<<512, 512, 0, stream>>>(trp, tloc, Yv, Abf,
                                         WT1 + (size_t)l * 256 * 256,
                                         WT2 + (size_t)l * CC * HIDDIM,
                                         xbi, xbo);
    }
    // after 8 layers (even count) the final x is in xbfA

    k_head<<<COORD_BLKS + (NN * MAXZV) / 256, 256, 0, stream>>>(ei, xbfA, wf, dirn,
                                                                Wa, ba, out);
}